// Round 2
// baseline (641.415 us; speedup 1.0000x reference)
//
#include <hip/hip_runtime.h>
#include <hip/hip_bf16.h>

#define NR 8192
#define DIN 200
#define DOUT 128
#define KSPLIT 4

typedef __attribute__((ext_vector_type(8))) short short8;
typedef __attribute__((ext_vector_type(4))) float f32x4;

__device__ __forceinline__ unsigned short f2bf(float x) {
    union { float f; unsigned u; } v; v.f = x;
    unsigned r = v.u + 0x7FFFu + ((v.u >> 16) & 1u);  // RNE
    return (unsigned short)(r >> 16);
}

// ---- K1: A2 = max(sigmoid(A),0.1) (f32 out + bf16 copy); dis = rsqrt(rowsum) ----
__global__ __launch_bounds__(256) void k_sig(const float* __restrict__ A,
                                             float* __restrict__ A2,
                                             unsigned short* __restrict__ A2b,
                                             float* __restrict__ dis) {
    const int row = blockIdx.x;
    const float4* __restrict__ ar = (const float4*)(A + (size_t)row * NR);
    float4* __restrict__ orow = (float4*)(A2 + (size_t)row * NR);
    ushort4* __restrict__ obr = (ushort4*)(A2b + (size_t)row * NR);
    float sum = 0.f;
#pragma unroll
    for (int i = 0; i < 8; ++i) {
        const int idx = i * 256 + threadIdx.x;
        float4 x = ar[idx];
        float4 s;
        s.x = fmaxf(__builtin_amdgcn_rcpf(1.f + __expf(-x.x)), 0.1f);
        s.y = fmaxf(__builtin_amdgcn_rcpf(1.f + __expf(-x.y)), 0.1f);
        s.z = fmaxf(__builtin_amdgcn_rcpf(1.f + __expf(-x.z)), 0.1f);
        s.w = fmaxf(__builtin_amdgcn_rcpf(1.f + __expf(-x.w)), 0.1f);
        orow[idx] = s;
        ushort4 pk;
        pk.x = f2bf(s.x); pk.y = f2bf(s.y); pk.z = f2bf(s.z); pk.w = f2bf(s.w);
        obr[idx] = pk;
        sum += (s.x + s.y) + (s.z + s.w);
    }
#pragma unroll
    for (int off = 32; off > 0; off >>= 1) sum += __shfl_down(sum, off, 64);
    __shared__ float red[4];
    if ((threadIdx.x & 63) == 0) red[threadIdx.x >> 6] = sum;
    __syncthreads();
    if (threadIdx.x == 0)
        dis[row] = __builtin_amdgcn_rsqf((red[0] + red[1]) + (red[2] + red[3]));
}

// ---- K2: VT[c][j] = bf16( dis[j] * (H[j,:]@W[:,c] + b[c]) ), K-major ----
#define VROWS 16
__global__ __launch_bounds__(256) void k_vt(const float* __restrict__ H,
                                            const float* __restrict__ W,
                                            const float* __restrict__ bias,
                                            const float* __restrict__ dis,
                                            unsigned short* __restrict__ VT) {
    __shared__ float hs[VROWS * 201];
    const int rowBase = blockIdx.x * VROWS;
    for (int i = threadIdx.x; i < VROWS * DIN; i += 256) {
        int r = i / DIN;
        int k = i - r * DIN;
        hs[r * 201 + k] = H[(size_t)rowBase * DIN + i];
    }
    __syncthreads();
    const int c0 = (threadIdx.x & 31) * 4;  // 4 cols
    const int rg = threadIdx.x >> 5;        // 8 groups x 2 rows
    float acc[2][4];
#pragma unroll
    for (int r = 0; r < 2; ++r)
#pragma unroll
        for (int i = 0; i < 4; ++i) acc[r][i] = 0.f;
#pragma unroll 4
    for (int k = 0; k < DIN; ++k) {
        float4 w4 = *(const float4*)(W + k * DOUT + c0);
#pragma unroll
        for (int r = 0; r < 2; ++r) {
            float h = hs[(rg * 2 + r) * 201 + k];
            acc[r][0] = fmaf(h, w4.x, acc[r][0]);
            acc[r][1] = fmaf(h, w4.y, acc[r][1]);
            acc[r][2] = fmaf(h, w4.z, acc[r][2]);
            acc[r][3] = fmaf(h, w4.w, acc[r][3]);
        }
    }
    float4 b4 = *(const float4*)(bias + c0);
    float bb[4] = {b4.x, b4.y, b4.z, b4.w};
    float d0 = dis[rowBase + rg * 2];
    float d1 = dis[rowBase + rg * 2 + 1];
#pragma unroll
    for (int i = 0; i < 4; ++i) {
        ushort2 pk;
        pk.x = f2bf(d0 * (acc[0][i] + bb[i]));
        pk.y = f2bf(d1 * (acc[1][i] + bb[i]));
        *(ushort2*)(VT + (size_t)(c0 + i) * NR + rowBase + rg * 2) = pk;
    }
}

// ---- K3: barrier-free streaming MFMA GEMM, fragments direct from global ----
// P[s] = A2b[:, ks] @ V[ks, :]; A2b bf16 row-major, VT bf16 K-major.
#define KR (NR / KSPLIT)   // 2048 K per block
#define NI (KR / 32)       // 64 iters of K=32

__global__ __launch_bounds__(256) void k_gemm(const unsigned short* __restrict__ A2b,
                                              const unsigned short* __restrict__ VT,
                                              float* __restrict__ P) {
    const int tid = threadIdx.x;
    const int blockRow = blockIdx.x & 255;
    const int s = blockIdx.x >> 8;
    const int rowBase = blockRow * 32;
    const int kb0 = s * KR;

    const int lane = tid & 63, w = tid >> 6;
    const int rt = w & 1, cg = w >> 1;        // wave tile: 16 rows x 64 cols
    const int fm = lane & 15, kq = lane >> 4; // frag: m/col = fm, k-quad = kq

    // A-frag: lane -> A2b[rowBase + rt*16 + fm][kb0 + kq*8 + j]  (16B contiguous)
    const unsigned short* __restrict__ ap =
        A2b + (size_t)(rowBase + rt * 16 + fm) * NR + kb0 + kq * 8;
    // B-frag: lane -> VT[cg*64 + nt*16 + fm][kb0 + kq*8 + j]     (16B contiguous)
    const unsigned short* __restrict__ bp =
        VT + (size_t)(cg * 64 + fm) * NR + kb0 + kq * 8;
    const size_t cstep = (size_t)16 * NR;  // nt col stride

    f32x4 acc[4];
#pragma unroll
    for (int nt = 0; nt < 4; ++nt) {
        acc[nt][0] = 0.f; acc[nt][1] = 0.f; acc[nt][2] = 0.f; acc[nt][3] = 0.f;
    }

    // register double-buffer, prefetch 2 K-iters deep (no LDS, no barriers)
    short8 a0, a1, b0[4], b1[4];
    a0 = *(const short8*)(ap);
    b0[0] = *(const short8*)(bp);
    b0[1] = *(const short8*)(bp + cstep);
    b0[2] = *(const short8*)(bp + 2 * cstep);
    b0[3] = *(const short8*)(bp + 3 * cstep);
    a1 = *(const short8*)(ap + 32);
    b1[0] = *(const short8*)(bp + 32);
    b1[1] = *(const short8*)(bp + 32 + cstep);
    b1[2] = *(const short8*)(bp + 32 + 2 * cstep);
    b1[3] = *(const short8*)(bp + 32 + 3 * cstep);

    for (int i = 0; i < NI; i += 2) {
        short8 at = a0, bt0 = b0[0], bt1 = b0[1], bt2 = b0[2], bt3 = b0[3];
        if (i + 2 < NI) {
            const unsigned short* a2p = ap + (i + 2) * 32;
            const unsigned short* b2p = bp + (i + 2) * 32;
            a0 = *(const short8*)(a2p);
            b0[0] = *(const short8*)(b2p);
            b0[1] = *(const short8*)(b2p + cstep);
            b0[2] = *(const short8*)(b2p + 2 * cstep);
            b0[3] = *(const short8*)(b2p + 3 * cstep);
        }
        acc[0] = __builtin_amdgcn_mfma_f32_16x16x32_bf16(at, bt0, acc[0], 0, 0, 0);
        acc[1] = __builtin_amdgcn_mfma_f32_16x16x32_bf16(at, bt1, acc[1], 0, 0, 0);
        acc[2] = __builtin_amdgcn_mfma_f32_16x16x32_bf16(at, bt2, acc[2], 0, 0, 0);
        acc[3] = __builtin_amdgcn_mfma_f32_16x16x32_bf16(at, bt3, acc[3], 0, 0, 0);

        short8 au = a1, bu0 = b1[0], bu1 = b1[1], bu2 = b1[2], bu3 = b1[3];
        if (i + 3 < NI) {
            const unsigned short* a3p = ap + (i + 3) * 32;
            const unsigned short* b3p = bp + (i + 3) * 32;
            a1 = *(const short8*)(a3p);
            b1[0] = *(const short8*)(b3p);
            b1[1] = *(const short8*)(b3p + cstep);
            b1[2] = *(const short8*)(b3p + 2 * cstep);
            b1[3] = *(const short8*)(b3p + 3 * cstep);
        }
        acc[0] = __builtin_amdgcn_mfma_f32_16x16x32_bf16(au, bu0, acc[0], 0, 0, 0);
        acc[1] = __builtin_amdgcn_mfma_f32_16x16x32_bf16(au, bu1, acc[1], 0, 0, 0);
        acc[2] = __builtin_amdgcn_mfma_f32_16x16x32_bf16(au, bu2, acc[2], 0, 0, 0);
        acc[3] = __builtin_amdgcn_mfma_f32_16x16x32_bf16(au, bu3, acc[3], 0, 0, 0);
    }

    // epilogue: f32 partials. C/D layout: col = lane&15, row = (lane>>4)*4 + reg
    float* __restrict__ Pp = P + (size_t)s * ((size_t)NR * DOUT);
    const int row0 = rowBase + rt * 16 + kq * 4;
    const int col0 = cg * 64 + fm;
#pragma unroll
    for (int nt = 0; nt < 4; ++nt) {
#pragma unroll
        for (int v = 0; v < 4; ++v) {
            Pp[(size_t)(row0 + v) * DOUT + col0 + nt * 16] = acc[nt][v];
        }
    }
}

// ---- K4: out = leaky( dis[i] * (P0+P1+P2+P3) ) ----
__global__ __launch_bounds__(256) void k_comb(const float* __restrict__ P,
                                              const float* __restrict__ dis,
                                              float* __restrict__ out) {
    const int idx = blockIdx.x * 256 + threadIdx.x;  // float4 index, 262144 total
    const float d = dis[idx >> 5];
    const size_t st = (size_t)NR * DOUT;
    const float* base = P + (size_t)idx * 4;
    float4 p0 = *(const float4*)(base);
    float4 p1 = *(const float4*)(base + st);
    float4 p2 = *(const float4*)(base + 2 * st);
    float4 p3 = *(const float4*)(base + 3 * st);
    float4 o;
    o.x = d * ((p0.x + p1.x) + (p2.x + p3.x)); o.x = o.x >= 0.f ? o.x : 0.01f * o.x;
    o.y = d * ((p0.y + p1.y) + (p2.y + p3.y)); o.y = o.y >= 0.f ? o.y : 0.01f * o.y;
    o.z = d * ((p0.z + p1.z) + (p2.z + p3.z)); o.z = o.z >= 0.f ? o.z : 0.01f * o.z;
    o.w = d * ((p0.w + p1.w) + (p2.w + p3.w)); o.w = o.w >= 0.f ? o.w : 0.01f * o.w;
    *(float4*)(out + (size_t)idx * 4) = o;
}

extern "C" void kernel_launch(void* const* d_in, const int* in_sizes, int n_in,
                              void* d_out, int out_size, void* d_ws, size_t ws_size,
                              hipStream_t stream) {
    const float* H = (const float*)d_in[0];
    const float* A = (const float*)d_in[1];
    const float* W = (const float*)d_in[2];
    const float* b = (const float*)d_in[3];

    float* out = (float*)d_out;                       // [8192,128]
    float* A2  = out + (size_t)NR * DOUT;             // [8192,8192] f32 (second output)

    char* ws = (char*)d_ws;
    float* dis = (float*)ws;                                   // 32 KB
    unsigned short* VT = (unsigned short*)(ws + 65536);        // 2 MB bf16 [128][8192]
    float* P = (float*)(ws + (4ull << 20));                    // 16 MB f32 [4][8192][128]
    unsigned short* A2b = (unsigned short*)(ws + (32ull << 20)); // 134 MB bf16 [8192][8192]

    k_sig <<<NR,          256, 0, stream>>>(A, A2, A2b, dis);
    k_vt  <<<NR / VROWS,  256, 0, stream>>>(H, W, b, dis, VT);
    k_gemm<<<256 * KSPLIT,256, 0, stream>>>(A2b, VT, P);
    k_comb<<<1024,        256, 0, stream>>>(P, dis, out);
}